// Round 7
// baseline (1317.293 us; speedup 1.0000x reference)
//
#include <hip/hip_runtime.h>
#include <cstddef>

#define NN 100000
#define NE 1600000
#define CB_SH 8                       // coarse bucket = 256 nodes
#define NCB ((NN + 255) >> CB_SH)     // 391 buckets
#define BIN_D 16
#define CAP 4608                      // per-bucket ebuf capacity (mean 4082 + 8.2 sigma), 9*512
#define SORT_D CAP
#define SC_BLOCKS 768
#define RPT 9                         // CAP / 512 register-staged records per thread

typedef unsigned int uint;
typedef unsigned short ushort;
typedef short bf16x8 __attribute__((ext_vector_type(8)));
typedef float f32x16 __attribute__((ext_vector_type(16)));

__device__ inline uint bf16_rne(float f) {   // fp32 -> bf16 bits (round-nearest-even)
  uint u = __float_as_uint(f);
  u += 0x7fffu + ((u >> 16) & 1u);
  return u >> 16;
}
__device__ inline float blo(uint u) { return __uint_as_float(u << 16); }
__device__ inline float bhi(uint u) { return __uint_as_float(u & 0xffff0000u); }

// ---------------- init: zero relative bucket cursors ----------------
__global__ void __launch_bounds__(512) k_init(int* __restrict__ gcur) {
  int i = threadIdx.x;
  if (i < NCB) gcur[i] = 0;
}

// ---------------- pass A: bin into coarse buckets (gcur = RELATIVE cursors) ----------------
// record: src (17b) | dst-low-8 (bits 17..24)
__global__ void __launch_bounds__(256) k_binA(const int* __restrict__ src,
                                              const int* __restrict__ dst,
                                              int* __restrict__ gcur,
                                              uint* __restrict__ ebuf, int E) {
  __shared__ uint bins[NCB][BIN_D + 1];   // +1 pad
  __shared__ uint bcnt[NCB];
  int t = threadIdx.x, lane = t & 63, wv = t >> 6;
  for (int j = t; j < NCB; j += 256) bcnt[j] = 0;
  const int per = (E + SC_BLOCKS - 1) / SC_BLOCKS;
  int e0 = blockIdx.x * per, e1 = min(E, e0 + per);
  __syncthreads();
  for (int rb = e0; rb < e1; rb += 2048) {
    #pragma unroll
    for (int r = 0; r < 8; ++r) {
      int i = rb + r * 256 + t;
      if (i < e1) {
        uint s = (uint)src[i], d = (uint)dst[i];
        uint b = d >> CB_SH;
        uint rec = s | ((d & 255u) << 17);
        uint slot = atomicAdd(&bcnt[b], 1u);
        if (slot < BIN_D) bins[b][slot] = rec;
        else ebuf[(size_t)b * CAP + atomicAdd(&gcur[b], 1)] = rec;  // rare overflow
      }
    }
    __syncthreads();
    // wave-cooperative coalesced flush: wave wv owns buckets wv, wv+4, ...
    for (int b = wv; b < NCB; b += 4) {
      uint c = bcnt[b]; if (c > BIN_D) c = BIN_D;
      if (c) {
        int base = 0;
        if (lane == 0) base = atomicAdd(&gcur[b], (int)c);
        base = __shfl(base, 0, 64);
        if (lane < (int)c) ebuf[(size_t)b * CAP + base + lane] = bins[b][lane];
      }
      if (lane == 0) bcnt[b] = 0;
    }
    __syncthreads();
  }
}

// ---------------- merged: degree count + scan -> row_ptr/dis + counting-sort scatter -> edges ----------------
// Records register-staged (static 9 slots) -> one ebuf read for the whole CSR finish.
__global__ void __launch_bounds__(512) k_csr(const uint* __restrict__ ebuf,
                                             const int* __restrict__ gcur,
                                             int* __restrict__ row_ptr,
                                             float* __restrict__ dis,
                                             uint* __restrict__ edges, int N, int E) {
  __shared__ uint sbuf[SORT_D];         // 18 KB
  __shared__ uint c[512];               // 256 node counters (+pad to block size)
  __shared__ uint wsum[8];
  int b = blockIdx.x, t = threadIdx.x, lane = t & 63, wv = t >> 6;
  c[t] = 0;

  // ebase = sum_{j<b} gcur[j]  (391 values, redundant per block)
  uint v = (t < b) ? (uint)gcur[t] : 0u;    // b <= 390 < 512
  #pragma unroll
  for (int d = 32; d; d >>= 1) v += __shfl_xor(v, d, 64);
  if (lane == 0) wsum[wv] = v;
  __syncthreads();                      // covers c[] init + wsum
  uint ebase = 0;
  #pragma unroll
  for (int j = 0; j < 8; ++j) ebase += wsum[j];

  int cntb = gcur[b];
  const uint* __restrict__ eb = ebuf + (size_t)b * CAP;
  uint rec[RPT];                        // static indices only (no scratch)
  #pragma unroll
  for (int j = 0; j < RPT; ++j) {
    int i = t + j * 512;
    rec[j] = (i < cntb) ? eb[i] : 0xffffffffu;   // valid records < 2^25
  }
  #pragma unroll
  for (int j = 0; j < RPT; ++j)
    if (rec[j] != 0xffffffffu) atomicAdd(&c[rec[j] >> 17], 1u);
  __syncthreads();

  // block exclusive scan over 256 counters (first 4 waves carry the data)
  uint deg = (t < 256) ? c[t] : 0u;
  uint x = deg;
  #pragma unroll
  for (int d = 1; d < 64; d <<= 1) {
    uint y = __shfl_up(x, (uint)d, 64);
    if (lane >= d) x += y;
  }
  if (lane == 63) wsum[wv] = x;
  __syncthreads();
  uint wexcl = 0;
  for (int j = 0; j < wv && j < 4; ++j) wexcl += wsum[j];
  uint excl = wexcl + (x - deg);        // bucket-local exclusive prefix

  int g = (b << CB_SH) + t;
  if (t < 256 && g < N) {
    row_ptr[g] = (int)(ebase + excl);
    dis[g] = rsqrtf((float)deg + 1.0f);
  }
  if (b == 0 && t == 0) row_ptr[N] = E;

  __syncthreads();                      // scan reads of c[] done before overwrite
  if (t < 256) c[t] = excl;             // counter array becomes cursor array
  __syncthreads();
  #pragma unroll
  for (int j = 0; j < RPT; ++j)
    if (rec[j] != 0xffffffffu) {
      int pos = atomicAdd(&c[rec[j] >> 17], 1u);   // pos < cntb <= SORT_D always
      sbuf[pos] = rec[j] & 0x1ffffu;
    }
  __syncthreads();
  for (int i = t; i < cntb; i += 512)
    edges[ebase + i] = sbuf[i];
}

// ---------------- MFMA bf16 GEMM: Hb[M][FOUT](bf16) = dis[m] * (X[M][128] @ W[128][FOUT]) ----------------
template <int FOUT, bool BF16IN>
__global__ void __launch_bounds__(256) k_gemm(const void* __restrict__ Xv,
                                              const float* __restrict__ W,
                                              const float* __restrict__ dis,
                                              ushort* __restrict__ Hb, int M) {
  constexpr int NCT = FOUT / 32;
  constexpr int TPW = NCT / 2;
  __shared__ alignas(16) ushort Af[2 * 8 * 64 * 8];
  __shared__ alignas(16) ushort Wf[NCT * 8 * 64 * 8];
  __shared__ float diss[64];
  int t = threadIdx.x, lane = t & 63, wv = t >> 6;
  int m0 = blockIdx.x * 64;

  if (t < 64) {
    int gm = m0 + t;
    diss[t] = (gm < M) ? dis[gm] : 0.f;
  }
  {
    int m = t >> 2;
    int gm = m0 + m;
    int rb = m >> 5, ml = m & 31;
    #pragma unroll
    for (int i = 0; i < 4; ++i) {
      int g = (t & 3) + i * 4;            // g = k>>3 in 0..15
      uint4 p = make_uint4(0u, 0u, 0u, 0u);
      if (gm < M) {
        if (BF16IN) {
          const ushort* X = (const ushort*)Xv;
          p = *reinterpret_cast<const uint4*>(X + (size_t)gm * 128 + g * 8);
        } else {
          const float* X = (const float*)Xv;
          float4 va = *reinterpret_cast<const float4*>(X + (size_t)gm * 128 + g * 8);
          float4 vb = *reinterpret_cast<const float4*>(X + (size_t)gm * 128 + g * 8 + 4);
          p.x = bf16_rne(va.x) | (bf16_rne(va.y) << 16);
          p.y = bf16_rne(va.z) | (bf16_rne(va.w) << 16);
          p.z = bf16_rne(vb.x) | (bf16_rne(vb.y) << 16);
          p.w = bf16_rne(vb.z) | (bf16_rne(vb.w) << 16);
        }
      }
      int kc = g >> 1, khi = g & 1;
      int ln = khi * 32 + ml;
      *reinterpret_cast<uint4*>(&Af[(((rb * 8 + kc) * 64) + ln) * 8]) = p;
    }
  }
  {
    constexpr int ITERS = 128 * FOUT / 4 / 256;
    #pragma unroll
    for (int it = 0; it < ITERS; ++it) {
      int lin = it * 256 + t;
      int k = lin / (FOUT / 4);
      int n = (lin % (FOUT / 4)) * 4;
      float4 vw = *reinterpret_cast<const float4*>(W + (size_t)k * FOUT + n);
      int kc = k >> 4, khi = (k >> 3) & 1, j = k & 7;
      float arr[4] = {vw.x, vw.y, vw.z, vw.w};
      #pragma unroll
      for (int e = 0; e < 4; ++e) {
        int nn = n + e;
        int c = nn >> 5;
        int ln = khi * 32 + (nn & 31);
        Wf[(((c * 8 + kc) * 64) + ln) * 8 + j] = (ushort)bf16_rne(arr[e]);
      }
    }
  }
  __syncthreads();

  f32x16 acc[TPW];
  #pragma unroll
  for (int tp = 0; tp < TPW; ++tp)
    #pragma unroll
    for (int r = 0; r < 16; ++r) acc[tp][r] = 0.f;

  int rb = wv & 1, cg = wv >> 1;
  #pragma unroll
  for (int kc = 0; kc < 8; ++kc) {
    bf16x8 a = *reinterpret_cast<bf16x8*>(&Af[((rb * 8 + kc) * 64 + lane) * 8]);
    #pragma unroll
    for (int tp = 0; tp < TPW; ++tp) {
      int c = cg * TPW + tp;
      bf16x8 bb = *reinterpret_cast<bf16x8*>(&Wf[((c * 8 + kc) * 64 + lane) * 8]);
      acc[tp] = __builtin_amdgcn_mfma_f32_32x32x16_bf16(a, bb, acc[tp], 0, 0, 0);
    }
  }

  // C/D layout: col=lane&31, row=(reg&3)+8*(reg>>2)+4*(lane>>5)
  #pragma unroll
  for (int tp = 0; tp < TPW; ++tp) {
    int col = (cg * TPW + tp) * 32 + (lane & 31);
    #pragma unroll
    for (int reg = 0; reg < 16; ++reg) {
      int lr = rb * 32 + 4 * (lane >> 5) + (reg & 3) + 8 * (reg >> 2);
      int row = m0 + lr;
      if (row < M) Hb[(size_t)row * FOUT + col] = (ushort)bf16_rne(acc[tp][reg] * diss[lr]);
    }
  }
}

// ---------------- aggregate F=128: one 16-lane group per node (4 nodes/wave), no reduction ----------------
__global__ void __launch_bounds__(256) k_agg128(const uint* __restrict__ hb,
                                                const int* __restrict__ row_ptr,
                                                const uint* __restrict__ edges,
                                                const float* __restrict__ dis,
                                                const float* __restrict__ bias,
                                                uint* __restrict__ outb, int N) {
  int t = threadIdx.x;
  int lane = t & 63, wv = t >> 6;
  int g16 = lane >> 4;                // node index within wave (0..3)
  int sl = lane & 15;                 // uint4 slot (8 features)
  int gbase = lane & 48;              // first lane of my 16-lane group
  int n = blockIdx.x * 16 + wv * 4 + g16;
  if (n >= N) return;
  const uint4* __restrict__ h4 = reinterpret_cast<const uint4*>(hb);  // 16 uint4/row
  int beg = row_ptr[n], end = row_ptr[n + 1];

  float acc[8];
  #pragma unroll
  for (int k = 0; k < 8; ++k) acc[k] = 0.f;

  int p = beg;
  for (; p + 8 <= end; p += 8) {        // 8 rows in flight per group (32/wave)
    uint r = edges[p + (lane & 7)];
    uint4 v[8];
    #pragma unroll
    for (int s = 0; s < 8; ++s) {
      uint rec = __shfl(r, gbase + s, 64);
      v[s] = h4[(size_t)rec * 16 + sl];
    }
    #pragma unroll
    for (int s = 0; s < 8; ++s) {
      acc[0] += blo(v[s].x);
      acc[1] += bhi(v[s].x);
      acc[2] += blo(v[s].y);
      acc[3] += bhi(v[s].y);
      acc[4] += blo(v[s].z);
      acc[5] += bhi(v[s].z);
      acc[6] += blo(v[s].w);
      acc[7] += bhi(v[s].w);
    }
  }
  if (p < end) {                        // remainder (<8), group-uniform guards
    int idx = p + (lane & 7);
    uint r = (idx < end) ? edges[idx] : 0u;
    #pragma unroll
    for (int s = 0; s < 8; ++s) {
      if (p + s < end) {
        uint rec = __shfl(r, gbase + s, 64);
        uint4 v = h4[(size_t)rec * 16 + sl];
        acc[0] += blo(v.x);
        acc[1] += bhi(v.x);
        acc[2] += blo(v.y);
        acc[3] += bhi(v.y);
        acc[4] += blo(v.z);
        acc[5] += bhi(v.z);
        acc[6] += blo(v.w);
        acc[7] += bhi(v.w);
      }
    }
  }

  float dn = dis[n];
  uint4 hv = h4[(size_t)n * 16 + sl];   // self row (already dis-scaled)
  const float4* b4 = reinterpret_cast<const float4*>(bias);
  float4 ba = b4[sl * 2], bb2 = b4[sl * 2 + 1];
  float o0 = fmaxf((acc[0] + blo(hv.x)) * dn + ba.x, 0.f);   // ReLU fused
  float o1 = fmaxf((acc[1] + bhi(hv.x)) * dn + ba.y, 0.f);
  float o2 = fmaxf((acc[2] + blo(hv.y)) * dn + ba.z, 0.f);
  float o3 = fmaxf((acc[3] + bhi(hv.y)) * dn + ba.w, 0.f);
  float o4 = fmaxf((acc[4] + blo(hv.z)) * dn + bb2.x, 0.f);
  float o5 = fmaxf((acc[5] + bhi(hv.z)) * dn + bb2.y, 0.f);
  float o6 = fmaxf((acc[6] + blo(hv.w)) * dn + bb2.z, 0.f);
  float o7 = fmaxf((acc[7] + bhi(hv.w)) * dn + bb2.w, 0.f);
  uint4 pb;
  pb.x = bf16_rne(o0) | (bf16_rne(o1) << 16);
  pb.y = bf16_rne(o2) | (bf16_rne(o3) << 16);
  pb.z = bf16_rne(o4) | (bf16_rne(o5) << 16);
  pb.w = bf16_rne(o6) | (bf16_rne(o7) << 16);
  reinterpret_cast<uint4*>(outb)[(size_t)n * 16 + sl] = pb;
}

// ---------------- aggregate F=64 + fused log_softmax: one 8-lane group per node (8 nodes/wave) ----------------
__global__ void __launch_bounds__(256) k_agg64(const uint* __restrict__ hb,
                                               const int* __restrict__ row_ptr,
                                               const uint* __restrict__ edges,
                                               const float* __restrict__ dis,
                                               const float* __restrict__ bias,
                                               float* __restrict__ out, int N) {
  int t = threadIdx.x;
  int lane = t & 63, wv = t >> 6;
  int g8 = lane >> 3;                 // node index within wave (0..7)
  int sl = lane & 7;                  // uint4 slot (8 features of 64)
  int gbase = lane & 56;              // first lane of my 8-lane group
  int n = blockIdx.x * 32 + wv * 8 + g8;
  if (n >= N) return;
  const uint4* __restrict__ h4 = reinterpret_cast<const uint4*>(hb);  // 8 uint4/row
  int beg = row_ptr[n], end = row_ptr[n + 1];

  float acc[8];
  #pragma unroll
  for (int k = 0; k < 8; ++k) acc[k] = 0.f;

  int p = beg;
  for (; p + 8 <= end; p += 8) {        // 8 rows in flight per group (64/wave)
    uint r = edges[p + sl];
    uint4 v[8];
    #pragma unroll
    for (int s = 0; s < 8; ++s) {
      uint rec = __shfl(r, gbase + s, 64);
      v[s] = h4[(size_t)rec * 8 + sl];
    }
    #pragma unroll
    for (int s = 0; s < 8; ++s) {
      acc[0] += blo(v[s].x);
      acc[1] += bhi(v[s].x);
      acc[2] += blo(v[s].y);
      acc[3] += bhi(v[s].y);
      acc[4] += blo(v[s].z);
      acc[5] += bhi(v[s].z);
      acc[6] += blo(v[s].w);
      acc[7] += bhi(v[s].w);
    }
  }
  if (p < end) {
    int idx = p + sl;
    uint r = (idx < end) ? edges[idx] : 0u;
    #pragma unroll
    for (int s = 0; s < 8; ++s) {
      if (p + s < end) {
        uint rec = __shfl(r, gbase + s, 64);
        uint4 v = h4[(size_t)rec * 8 + sl];
        acc[0] += blo(v.x);
        acc[1] += bhi(v.x);
        acc[2] += blo(v.y);
        acc[3] += bhi(v.y);
        acc[4] += blo(v.z);
        acc[5] += bhi(v.z);
        acc[6] += blo(v.w);
        acc[7] += bhi(v.w);
      }
    }
  }

  float dn = dis[n];
  uint4 hv = h4[(size_t)n * 8 + sl];    // self row (already dis-scaled)
  const float4* b4 = reinterpret_cast<const float4*>(bias);
  float4 ba = b4[sl * 2], bb2 = b4[sl * 2 + 1];
  float z[8];
  z[0] = (acc[0] + blo(hv.x)) * dn + ba.x;
  z[1] = (acc[1] + bhi(hv.x)) * dn + ba.y;
  z[2] = (acc[2] + blo(hv.y)) * dn + ba.z;
  z[3] = (acc[3] + bhi(hv.y)) * dn + ba.w;
  z[4] = (acc[4] + blo(hv.z)) * dn + bb2.x;
  z[5] = (acc[5] + bhi(hv.z)) * dn + bb2.y;
  z[6] = (acc[6] + blo(hv.w)) * dn + bb2.z;
  z[7] = (acc[7] + bhi(hv.w)) * dn + bb2.w;

  float m = z[0];
  #pragma unroll
  for (int k = 1; k < 8; ++k) m = fmaxf(m, z[k]);
  m = fmaxf(m, __shfl_xor(m, 1, 64));
  m = fmaxf(m, __shfl_xor(m, 2, 64));
  m = fmaxf(m, __shfl_xor(m, 4, 64));
  float e = 0.f;
  #pragma unroll
  for (int k = 0; k < 8; ++k) e += __expf(z[k] - m);
  e += __shfl_xor(e, 1, 64);
  e += __shfl_xor(e, 2, 64);
  e += __shfl_xor(e, 4, 64);
  float lse = m + __logf(e);

  float4* orow = reinterpret_cast<float4*>(out + (size_t)n * 64);
  orow[sl * 2]     = make_float4(z[0] - lse, z[1] - lse, z[2] - lse, z[3] - lse);
  orow[sl * 2 + 1] = make_float4(z[4] - lse, z[5] - lse, z[6] - lse, z[7] - lse);
}

extern "C" void kernel_launch(void* const* d_in, const int* in_sizes, int n_in,
                              void* d_out, int out_size, void* d_ws, size_t ws_size,
                              hipStream_t stream) {
  const float* x  = (const float*)d_in[0];
  const int*   ei = (const int*)d_in[1];
  const float* W0 = (const float*)d_in[2];
  const float* b0 = (const float*)d_in[3];
  const float* W1 = (const float*)d_in[4];
  const float* b1 = (const float*)d_in[5];
  const float* W2 = (const float*)d_in[6];
  const float* b2 = (const float*)d_in[7];
  float* out = (float*)d_out;

  const int N = NN, E = NE;
  const int* src = ei;
  const int* dst = ei + E;

  char* ws = (char*)d_ws;
  size_t off = 0;
  auto alloc = [&](size_t bytes) -> void* {
    off = (off + 255) & ~(size_t)255;
    void* p = ws + off;
    off += bytes;
    return p;
  };
  float*  dis     = (float*)alloc((size_t)N * 4);
  int*    row_ptr = (int*)alloc((size_t)(N + 1) * 4);
  int*    gcur    = (int*)alloc((size_t)NCB * 4);
  uint*   ebuf    = (uint*)alloc((size_t)NCB * CAP * 4);
  uint*   edges   = (uint*)alloc((size_t)E * 4);
  ushort* bufAb   = (ushort*)alloc((size_t)N * 128 * 2);  // gemm bf16 out
  ushort* bufBb   = (ushort*)alloc((size_t)N * 128 * 2);  // agg bf16 out / gemm in

  // ---- CSR build ----
  k_init<<<1, 512, 0, stream>>>(gcur);
  k_binA<<<SC_BLOCKS, 256, 0, stream>>>(src, dst, gcur, ebuf, E);
  k_csr<<<NCB, 512, 0, stream>>>(ebuf, gcur, row_ptr, dis, edges, N, E);

  const int gemm_grid = (N + 63) / 64;    // 1563
  const int agg128_grid = (N + 15) / 16;  // 6250 (16 nodes/block, 4 per wave)
  const int agg64_grid = (N + 31) / 32;   // 3125 (32 nodes/block, 8 per wave)

  // ---- layer 0 ----
  k_gemm<128, false><<<gemm_grid, 256, 0, stream>>>(x, W0, dis, bufAb, N);
  k_agg128<<<agg128_grid, 256, 0, stream>>>((const uint*)bufAb, row_ptr, edges, dis, b0, (uint*)bufBb, N);
  // ---- layer 1 ----
  k_gemm<128, true><<<gemm_grid, 256, 0, stream>>>(bufBb, W1, dis, bufAb, N);
  k_agg128<<<agg128_grid, 256, 0, stream>>>((const uint*)bufAb, row_ptr, edges, dis, b1, (uint*)bufBb, N);
  // ---- layer 2 (fused log_softmax epilogue) ----
  k_gemm<64, true><<<gemm_grid, 256, 0, stream>>>(bufBb, W2, dis, bufAb, N);
  k_agg64<<<agg64_grid, 256, 0, stream>>>((const uint*)bufAb, row_ptr, edges, dis, b2, out, N);
}

// Round 8
// 347.439 us; speedup vs baseline: 3.7914x; 3.7914x over previous
//
#include <hip/hip_runtime.h>
#include <cstddef>

#define NN 100000
#define NE 1600000
#define CB_SH 9                       // coarse bucket = 512 nodes
#define NCB ((NN + 511) >> CB_SH)     // 196 buckets
#define BIN_D 32
#define CAP 8960                      // per-bucket ebuf capacity (mean 8192 + 8.5 sigma)
#define SORT_D CAP
#define SC_BLOCKS 800                 // per = 2000 <= 2048 -> exactly ONE bin+flush round
#define RPT 18                        // ceil(CAP / 512) register-staged records per thread

typedef unsigned int uint;
typedef unsigned short ushort;
typedef short bf16x8 __attribute__((ext_vector_type(8)));
typedef float f32x16 __attribute__((ext_vector_type(16)));

__device__ inline uint bf16_rne(float f) {   // fp32 -> bf16 bits (round-nearest-even)
  uint u = __float_as_uint(f);
  u += 0x7fffu + ((u >> 16) & 1u);
  return u >> 16;
}
__device__ inline float blo(uint u) { return __uint_as_float(u << 16); }
__device__ inline float bhi(uint u) { return __uint_as_float(u & 0xffff0000u); }

// ---------------- init: zero relative bucket cursors ----------------
__global__ void __launch_bounds__(256) k_init(int* __restrict__ gcur) {
  int i = threadIdx.x;
  if (i < NCB) gcur[i] = 0;
}

// ---------------- pack W (fp32, row-major) -> bf16 in the exact GEMM LDS fragment layout ----------------
// Wf index: (((c*8 + kc)*64) + ln)*8 + j, c=n>>5, kc=k>>4, khi=(k>>3)&1, ln=khi*32+(n&31), j=k&7
__global__ void __launch_bounds__(256) k_pack(const float* __restrict__ W0,
                                              const float* __restrict__ W1,
                                              const float* __restrict__ W2,
                                              ushort* __restrict__ W0b,
                                              ushort* __restrict__ W1b,
                                              ushort* __restrict__ W2b) {
  int b = blockIdx.x, t = threadIdx.x;
  const float* W = (b == 0) ? W0 : (b == 1) ? W1 : W2;
  ushort* Wb = (b == 0) ? W0b : (b == 1) ? W1b : W2b;
  int FOUT = (b == 2) ? 64 : 128;
  for (int lin = t; lin < 128 * FOUT; lin += 256) {
    int k = lin / FOUT, n = lin % FOUT;
    int c = n >> 5, kc = k >> 4, khi = (k >> 3) & 1, j = k & 7;
    int ln = khi * 32 + (n & 31);
    Wb[(((c * 8 + kc) * 64) + ln) * 8 + j] = (ushort)bf16_rne(W[lin]);
  }
}

// ---------------- pass A: bin into coarse buckets (gcur = RELATIVE cursors) ----------------
// record: src (17b) | dst-low-9 (bits 17..25). ONE round per block (per <= 2048).
__global__ void __launch_bounds__(256) k_binA(const int* __restrict__ src,
                                              const int* __restrict__ dst,
                                              int* __restrict__ gcur,
                                              uint* __restrict__ ebuf, int E) {
  __shared__ uint bins[NCB][BIN_D + 1];   // +1 pad
  __shared__ uint bcnt[NCB];
  int t = threadIdx.x;
  for (int j = t; j < NCB; j += 256) bcnt[j] = 0;
  const int per = (E + SC_BLOCKS - 1) / SC_BLOCKS;   // 2000
  int e0 = blockIdx.x * per, e1 = min(E, e0 + per);
  __syncthreads();
  #pragma unroll
  for (int r = 0; r < 8; ++r) {
    int i = e0 + r * 256 + t;
    if (i < e1) {
      uint s = (uint)src[i], d = (uint)dst[i];
      uint b = d >> CB_SH;
      uint rec = s | ((d & 511u) << 17);
      uint slot = atomicAdd(&bcnt[b], 1u);
      if (slot < BIN_D) bins[b][slot] = rec;
      else ebuf[(size_t)b * CAP + atomicAdd(&gcur[b], 1)] = rec;  // rare overflow
    }
  }
  __syncthreads();
  if (t < NCB) {                      // one thread per bucket: parallel flush
    uint c = bcnt[t]; if (c > BIN_D) c = BIN_D;
    if (c) {
      int base = atomicAdd(&gcur[t], (int)c);
      for (uint i = 0; i < c; ++i) ebuf[(size_t)t * CAP + base + i] = bins[t][i];
    }
  }
}

// ---------------- merged: degree count + scan -> row_ptr/dis + counting-sort scatter -> edges ----------------
// Records register-staged (static 18 slots) -> one ebuf read for the whole CSR finish.
__global__ void __launch_bounds__(512) k_csr(const uint* __restrict__ ebuf,
                                             const int* __restrict__ gcur,
                                             int* __restrict__ row_ptr,
                                             float* __restrict__ dis,
                                             uint* __restrict__ edges, int N, int E) {
  __shared__ uint sbuf[SORT_D];         // 35 KB
  __shared__ uint c[512];
  __shared__ uint wsum[8];
  int b = blockIdx.x, t = threadIdx.x, lane = t & 63, wv = t >> 6;
  c[t] = 0;

  // ebase = sum_{j<b} gcur[j]  (196 values, redundant per block)
  uint v = (t < b) ? (uint)gcur[t] : 0u;    // t<b<=195 implies t<NCB
  #pragma unroll
  for (int d = 32; d; d >>= 1) v += __shfl_xor(v, d, 64);
  if (lane == 0) wsum[wv] = v;
  __syncthreads();                      // covers c[] init + wsum
  uint ebase = 0;
  #pragma unroll
  for (int j = 0; j < 8; ++j) ebase += wsum[j];

  int cntb = gcur[b];
  const uint* __restrict__ eb = ebuf + (size_t)b * CAP;
  uint rec[RPT];                        // static indices only (no scratch)
  #pragma unroll
  for (int j = 0; j < RPT; ++j) {
    int i = t + j * 512;
    rec[j] = (i < cntb) ? eb[i] : 0xffffffffu;   // valid records < 2^26
  }
  #pragma unroll
  for (int j = 0; j < RPT; ++j)
    if (rec[j] != 0xffffffffu) atomicAdd(&c[rec[j] >> 17], 1u);
  __syncthreads();

  // block exclusive scan over 512 counters
  uint deg = c[t];
  uint x = deg;
  #pragma unroll
  for (int d = 1; d < 64; d <<= 1) {
    uint y = __shfl_up(x, (uint)d, 64);
    if (lane >= d) x += y;
  }
  if (lane == 63) wsum[wv] = x;
  __syncthreads();
  uint wexcl = 0;
  for (int j = 0; j < wv; ++j) wexcl += wsum[j];
  uint excl = wexcl + (x - deg);        // bucket-local exclusive prefix

  int g = (b << CB_SH) + t;
  if (g < N) {
    row_ptr[g] = (int)(ebase + excl);
    dis[g] = rsqrtf((float)deg + 1.0f);
  }
  if (b == 0 && t == 0) row_ptr[N] = E;

  c[t] = excl;                          // counter array becomes cursor array
  __syncthreads();
  #pragma unroll
  for (int j = 0; j < RPT; ++j)
    if (rec[j] != 0xffffffffu) {
      int pos = atomicAdd(&c[rec[j] >> 17], 1u);   // pos < cntb <= SORT_D always
      sbuf[pos] = rec[j] & 0x1ffffu;
    }
  __syncthreads();
  for (int i = t; i < cntb; i += 512)
    edges[ebase + i] = sbuf[i];
}

// ---------------- MFMA bf16 GEMM: Hb[M][FOUT](bf16) = dis[m] * (X[M][128] @ W[128][FOUT]) ----------------
// W pre-packed (k_pack) in LDS fragment layout -> staging is a straight uint4 copy.
template <int FOUT, bool BF16IN>
__global__ void __launch_bounds__(256) k_gemm(const void* __restrict__ Xv,
                                              const ushort* __restrict__ Wb,
                                              const float* __restrict__ dis,
                                              ushort* __restrict__ Hb, int M) {
  constexpr int NCT = FOUT / 32;
  constexpr int TPW = NCT / 2;
  __shared__ alignas(16) ushort Af[2 * 8 * 64 * 8];
  __shared__ alignas(16) ushort Wf[NCT * 8 * 64 * 8];
  __shared__ float diss[64];
  int t = threadIdx.x, lane = t & 63, wv = t >> 6;
  int m0 = blockIdx.x * 64;

  if (t < 64) {
    int gm = m0 + t;
    diss[t] = (gm < M) ? dis[gm] : 0.f;
  }
  {
    int m = t >> 2;
    int gm = m0 + m;
    int rb = m >> 5, ml = m & 31;
    #pragma unroll
    for (int i = 0; i < 4; ++i) {
      int g = (t & 3) + i * 4;            // g = k>>3 in 0..15
      uint4 p = make_uint4(0u, 0u, 0u, 0u);
      if (gm < M) {
        if (BF16IN) {
          const ushort* X = (const ushort*)Xv;
          p = *reinterpret_cast<const uint4*>(X + (size_t)gm * 128 + g * 8);
        } else {
          const float* X = (const float*)Xv;
          float4 va = *reinterpret_cast<const float4*>(X + (size_t)gm * 128 + g * 8);
          float4 vb = *reinterpret_cast<const float4*>(X + (size_t)gm * 128 + g * 8 + 4);
          p.x = bf16_rne(va.x) | (bf16_rne(va.y) << 16);
          p.y = bf16_rne(va.z) | (bf16_rne(va.w) << 16);
          p.z = bf16_rne(vb.x) | (bf16_rne(vb.y) << 16);
          p.w = bf16_rne(vb.z) | (bf16_rne(vb.w) << 16);
        }
      }
      int kc = g >> 1, khi = g & 1;
      int ln = khi * 32 + ml;
      *reinterpret_cast<uint4*>(&Af[(((rb * 8 + kc) * 64) + ln) * 8]) = p;
    }
  }
  {
    constexpr int WU4 = 128 * FOUT * 2 / 16;   // uint4 count: 2048 (FOUT=128) / 1024 (FOUT=64)
    #pragma unroll
    for (int it = 0; it < WU4 / 256; ++it) {
      int idx = it * 256 + t;
      reinterpret_cast<uint4*>(Wf)[idx] = reinterpret_cast<const uint4*>(Wb)[idx];
    }
  }
  __syncthreads();

  f32x16 acc[TPW];
  #pragma unroll
  for (int tp = 0; tp < TPW; ++tp)
    #pragma unroll
    for (int r = 0; r < 16; ++r) acc[tp][r] = 0.f;

  int rb = wv & 1, cg = wv >> 1;
  #pragma unroll
  for (int kc = 0; kc < 8; ++kc) {
    bf16x8 a = *reinterpret_cast<bf16x8*>(&Af[((rb * 8 + kc) * 64 + lane) * 8]);
    #pragma unroll
    for (int tp = 0; tp < TPW; ++tp) {
      int c = cg * TPW + tp;
      bf16x8 bb = *reinterpret_cast<bf16x8*>(&Wf[((c * 8 + kc) * 64 + lane) * 8]);
      acc[tp] = __builtin_amdgcn_mfma_f32_32x32x16_bf16(a, bb, acc[tp], 0, 0, 0);
    }
  }

  // C/D layout: col=lane&31, row=(reg&3)+8*(reg>>2)+4*(lane>>5)
  #pragma unroll
  for (int tp = 0; tp < TPW; ++tp) {
    int col = (cg * TPW + tp) * 32 + (lane & 31);
    #pragma unroll
    for (int reg = 0; reg < 16; ++reg) {
      int lr = rb * 32 + 4 * (lane >> 5) + (reg & 3) + 8 * (reg >> 2);
      int row = m0 + lr;
      if (row < M) Hb[(size_t)row * FOUT + col] = (ushort)bf16_rne(acc[tp][reg] * diss[lr]);
    }
  }
}

// ---------------- aggregate F=128: one 16-lane group per node (4 nodes/wave), no reduction ----------------
__global__ void __launch_bounds__(256) k_agg128(const uint* __restrict__ hb,
                                                const int* __restrict__ row_ptr,
                                                const uint* __restrict__ edges,
                                                const float* __restrict__ dis,
                                                const float* __restrict__ bias,
                                                uint* __restrict__ outb, int N) {
  int t = threadIdx.x;
  int lane = t & 63, wv = t >> 6;
  int g16 = lane >> 4;                // node index within wave (0..3)
  int sl = lane & 15;                 // uint4 slot (8 features)
  int gbase = lane & 48;              // first lane of my 16-lane group
  int n = blockIdx.x * 16 + wv * 4 + g16;
  if (n >= N) return;
  const uint4* __restrict__ h4 = reinterpret_cast<const uint4*>(hb);  // 16 uint4/row
  int beg = row_ptr[n], end = row_ptr[n + 1];

  float acc[8];
  #pragma unroll
  for (int k = 0; k < 8; ++k) acc[k] = 0.f;

  int p = beg;
  for (; p + 8 <= end; p += 8) {        // 8 rows in flight per group (32/wave)
    uint r = edges[p + (lane & 7)];
    uint4 v[8];
    #pragma unroll
    for (int s = 0; s < 8; ++s) {
      uint rec = __shfl(r, gbase + s, 64);
      v[s] = h4[(size_t)rec * 16 + sl];
    }
    #pragma unroll
    for (int s = 0; s < 8; ++s) {
      acc[0] += blo(v[s].x);
      acc[1] += bhi(v[s].x);
      acc[2] += blo(v[s].y);
      acc[3] += bhi(v[s].y);
      acc[4] += blo(v[s].z);
      acc[5] += bhi(v[s].z);
      acc[6] += blo(v[s].w);
      acc[7] += bhi(v[s].w);
    }
  }
  if (p < end) {                        // remainder (<8), group-uniform guards
    int idx = p + (lane & 7);
    uint r = (idx < end) ? edges[idx] : 0u;
    #pragma unroll
    for (int s = 0; s < 8; ++s) {
      if (p + s < end) {
        uint rec = __shfl(r, gbase + s, 64);
        uint4 v = h4[(size_t)rec * 16 + sl];
        acc[0] += blo(v.x);
        acc[1] += bhi(v.x);
        acc[2] += blo(v.y);
        acc[3] += bhi(v.y);
        acc[4] += blo(v.z);
        acc[5] += bhi(v.z);
        acc[6] += blo(v.w);
        acc[7] += bhi(v.w);
      }
    }
  }

  float dn = dis[n];
  uint4 hv = h4[(size_t)n * 16 + sl];   // self row (already dis-scaled)
  const float4* b4 = reinterpret_cast<const float4*>(bias);
  float4 ba = b4[sl * 2], bb2 = b4[sl * 2 + 1];
  float o0 = fmaxf((acc[0] + blo(hv.x)) * dn + ba.x, 0.f);   // ReLU fused
  float o1 = fmaxf((acc[1] + bhi(hv.x)) * dn + ba.y, 0.f);
  float o2 = fmaxf((acc[2] + blo(hv.y)) * dn + ba.z, 0.f);
  float o3 = fmaxf((acc[3] + bhi(hv.y)) * dn + ba.w, 0.f);
  float o4 = fmaxf((acc[4] + blo(hv.z)) * dn + bb2.x, 0.f);
  float o5 = fmaxf((acc[5] + bhi(hv.z)) * dn + bb2.y, 0.f);
  float o6 = fmaxf((acc[6] + blo(hv.w)) * dn + bb2.z, 0.f);
  float o7 = fmaxf((acc[7] + bhi(hv.w)) * dn + bb2.w, 0.f);
  uint4 pb;
  pb.x = bf16_rne(o0) | (bf16_rne(o1) << 16);
  pb.y = bf16_rne(o2) | (bf16_rne(o3) << 16);
  pb.z = bf16_rne(o4) | (bf16_rne(o5) << 16);
  pb.w = bf16_rne(o6) | (bf16_rne(o7) << 16);
  reinterpret_cast<uint4*>(outb)[(size_t)n * 16 + sl] = pb;
}

// ---------------- aggregate F=64 + fused log_softmax: one 8-lane group per node (8 nodes/wave) ----------------
__global__ void __launch_bounds__(256) k_agg64(const uint* __restrict__ hb,
                                               const int* __restrict__ row_ptr,
                                               const uint* __restrict__ edges,
                                               const float* __restrict__ dis,
                                               const float* __restrict__ bias,
                                               float* __restrict__ out, int N) {
  int t = threadIdx.x;
  int lane = t & 63, wv = t >> 6;
  int g8 = lane >> 3;                 // node index within wave (0..7)
  int sl = lane & 7;                  // uint4 slot (8 features of 64)
  int gbase = lane & 56;              // first lane of my 8-lane group
  int n = blockIdx.x * 32 + wv * 8 + g8;
  if (n >= N) return;
  const uint4* __restrict__ h4 = reinterpret_cast<const uint4*>(hb);  // 8 uint4/row
  int beg = row_ptr[n], end = row_ptr[n + 1];

  float acc[8];
  #pragma unroll
  for (int k = 0; k < 8; ++k) acc[k] = 0.f;

  int p = beg;
  for (; p + 8 <= end; p += 8) {        // 8 rows in flight per group (64/wave)
    uint r = edges[p + sl];
    uint4 v[8];
    #pragma unroll
    for (int s = 0; s < 8; ++s) {
      uint rec = __shfl(r, gbase + s, 64);
      v[s] = h4[(size_t)rec * 8 + sl];
    }
    #pragma unroll
    for (int s = 0; s < 8; ++s) {
      acc[0] += blo(v[s].x);
      acc[1] += bhi(v[s].x);
      acc[2] += blo(v[s].y);
      acc[3] += bhi(v[s].y);
      acc[4] += blo(v[s].z);
      acc[5] += bhi(v[s].z);
      acc[6] += blo(v[s].w);
      acc[7] += bhi(v[s].w);
    }
  }
  if (p < end) {
    int idx = p + sl;
    uint r = (idx < end) ? edges[idx] : 0u;
    #pragma unroll
    for (int s = 0; s < 8; ++s) {
      if (p + s < end) {
        uint rec = __shfl(r, gbase + s, 64);
        uint4 v = h4[(size_t)rec * 8 + sl];
        acc[0] += blo(v.x);
        acc[1] += bhi(v.x);
        acc[2] += blo(v.y);
        acc[3] += bhi(v.y);
        acc[4] += blo(v.z);
        acc[5] += bhi(v.z);
        acc[6] += blo(v.w);
        acc[7] += bhi(v.w);
      }
    }
  }

  float dn = dis[n];
  uint4 hv = h4[(size_t)n * 8 + sl];    // self row (already dis-scaled)
  const float4* b4 = reinterpret_cast<const float4*>(bias);
  float4 ba = b4[sl * 2], bb2 = b4[sl * 2 + 1];
  float z[8];
  z[0] = (acc[0] + blo(hv.x)) * dn + ba.x;
  z[1] = (acc[1] + bhi(hv.x)) * dn + ba.y;
  z[2] = (acc[2] + blo(hv.y)) * dn + ba.z;
  z[3] = (acc[3] + bhi(hv.y)) * dn + ba.w;
  z[4] = (acc[4] + blo(hv.z)) * dn + bb2.x;
  z[5] = (acc[5] + bhi(hv.z)) * dn + bb2.y;
  z[6] = (acc[6] + blo(hv.w)) * dn + bb2.z;
  z[7] = (acc[7] + bhi(hv.w)) * dn + bb2.w;

  float m = z[0];
  #pragma unroll
  for (int k = 1; k < 8; ++k) m = fmaxf(m, z[k]);
  m = fmaxf(m, __shfl_xor(m, 1, 64));
  m = fmaxf(m, __shfl_xor(m, 2, 64));
  m = fmaxf(m, __shfl_xor(m, 4, 64));
  float e = 0.f;
  #pragma unroll
  for (int k = 0; k < 8; ++k) e += __expf(z[k] - m);
  e += __shfl_xor(e, 1, 64);
  e += __shfl_xor(e, 2, 64);
  e += __shfl_xor(e, 4, 64);
  float lse = m + __logf(e);

  float4* orow = reinterpret_cast<float4*>(out + (size_t)n * 64);
  orow[sl * 2]     = make_float4(z[0] - lse, z[1] - lse, z[2] - lse, z[3] - lse);
  orow[sl * 2 + 1] = make_float4(z[4] - lse, z[5] - lse, z[6] - lse, z[7] - lse);
}

extern "C" void kernel_launch(void* const* d_in, const int* in_sizes, int n_in,
                              void* d_out, int out_size, void* d_ws, size_t ws_size,
                              hipStream_t stream) {
  const float* x  = (const float*)d_in[0];
  const int*   ei = (const int*)d_in[1];
  const float* W0 = (const float*)d_in[2];
  const float* b0 = (const float*)d_in[3];
  const float* W1 = (const float*)d_in[4];
  const float* b1 = (const float*)d_in[5];
  const float* W2 = (const float*)d_in[6];
  const float* b2 = (const float*)d_in[7];
  float* out = (float*)d_out;

  const int N = NN, E = NE;
  const int* src = ei;
  const int* dst = ei + E;

  char* ws = (char*)d_ws;
  size_t off = 0;
  auto alloc = [&](size_t bytes) -> void* {
    off = (off + 255) & ~(size_t)255;
    void* p = ws + off;
    off += bytes;
    return p;
  };
  float*  dis     = (float*)alloc((size_t)N * 4);
  int*    row_ptr = (int*)alloc((size_t)(N + 1) * 4);
  int*    gcur    = (int*)alloc((size_t)NCB * 4);
  uint*   ebuf    = (uint*)alloc((size_t)NCB * CAP * 4);
  uint*   edges   = (uint*)alloc((size_t)E * 4);
  ushort* bufAb   = (ushort*)alloc((size_t)N * 128 * 2);  // gemm bf16 out
  ushort* bufBb   = (ushort*)alloc((size_t)N * 128 * 2);  // agg bf16 out / gemm in
  ushort* W0b     = (ushort*)alloc(128 * 128 * 2);
  ushort* W1b     = (ushort*)alloc(128 * 128 * 2);
  ushort* W2b     = (ushort*)alloc(128 * 64 * 2);

  // ---- CSR build + weight pre-pack ----
  k_init<<<1, 256, 0, stream>>>(gcur);
  k_pack<<<3, 256, 0, stream>>>(W0, W1, W2, W0b, W1b, W2b);
  k_binA<<<SC_BLOCKS, 256, 0, stream>>>(src, dst, gcur, ebuf, E);
  k_csr<<<NCB, 512, 0, stream>>>(ebuf, gcur, row_ptr, dis, edges, N, E);

  const int gemm_grid = (N + 63) / 64;    // 1563
  const int agg128_grid = (N + 15) / 16;  // 6250 (16 nodes/block, 4 per wave)
  const int agg64_grid = (N + 31) / 32;   // 3125 (32 nodes/block, 8 per wave)

  // ---- layer 0 ----
  k_gemm<128, false><<<gemm_grid, 256, 0, stream>>>(x, W0b, dis, bufAb, N);
  k_agg128<<<agg128_grid, 256, 0, stream>>>((const uint*)bufAb, row_ptr, edges, dis, b0, (uint*)bufBb, N);
  // ---- layer 1 ----
  k_gemm<128, true><<<gemm_grid, 256, 0, stream>>>(bufBb, W1b, dis, bufAb, N);
  k_agg128<<<agg128_grid, 256, 0, stream>>>((const uint*)bufAb, row_ptr, edges, dis, b1, (uint*)bufBb, N);
  // ---- layer 2 (fused log_softmax epilogue) ----
  k_gemm<64, true><<<gemm_grid, 256, 0, stream>>>(bufBb, W2b, dis, bufAb, N);
  k_agg64<<<agg64_grid, 256, 0, stream>>>((const uint*)bufAb, row_ptr, edges, dis, b2, out, N);
}

// Round 9
// 338.871 us; speedup vs baseline: 3.8873x; 1.0253x over previous
//
#include <hip/hip_runtime.h>
#include <cstddef>

#define NN 100000
#define NE 1600000
#define CB_SH 9                       // coarse bucket = 512 nodes
#define NCB ((NN + 511) >> CB_SH)     // 196 buckets
#define BIN_D 32
#define CAP 8960                      // per-bucket ebuf capacity (mean 8192 + 8.5 sigma)
#define SORT_D CAP
#define SC_BLOCKS 800                 // per = 2000 <= 2048 -> exactly ONE bin+flush round
#define RPT 18                        // ceil(CAP / 512) register-staged records per thread

typedef unsigned int uint;
typedef unsigned short ushort;
typedef short bf16x8 __attribute__((ext_vector_type(8)));
typedef float f32x16 __attribute__((ext_vector_type(16)));

__device__ inline uint bf16_rne(float f) {   // fp32 -> bf16 bits (round-nearest-even)
  uint u = __float_as_uint(f);
  u += 0x7fffu + ((u >> 16) & 1u);
  return u >> 16;
}
__device__ inline float blo(uint u) { return __uint_as_float(u << 16); }
__device__ inline float bhi(uint u) { return __uint_as_float(u & 0xffff0000u); }

// ---------------- setup: blocks 0-2 pack W -> bf16 fragment layout; block 3 zeros cursors ----------------
// Wf index: (((c*8 + kc)*64) + ln)*8 + j, c=n>>5, kc=k>>4, khi=(k>>3)&1, ln=khi*32+(n&31), j=k&7
__global__ void __launch_bounds__(256) k_setup(const float* __restrict__ W0,
                                               const float* __restrict__ W1,
                                               const float* __restrict__ W2,
                                               ushort* __restrict__ W0b,
                                               ushort* __restrict__ W1b,
                                               ushort* __restrict__ W2b,
                                               int* __restrict__ gcur) {
  int b = blockIdx.x, t = threadIdx.x;
  if (b == 3) {
    if (t < NCB) gcur[t] = 0;
    return;
  }
  const float* W = (b == 0) ? W0 : (b == 1) ? W1 : W2;
  ushort* Wb = (b == 0) ? W0b : (b == 1) ? W1b : W2b;
  int FOUT = (b == 2) ? 64 : 128;
  for (int lin = t; lin < 128 * FOUT; lin += 256) {
    int k = lin / FOUT, n = lin % FOUT;
    int c = n >> 5, kc = k >> 4, khi = (k >> 3) & 1, j = k & 7;
    int ln = khi * 32 + (n & 31);
    Wb[(((c * 8 + kc) * 64) + ln) * 8 + j] = (ushort)bf16_rne(W[lin]);
  }
}

// ---------------- pass A: bin into coarse buckets (gcur = RELATIVE cursors) ----------------
// record: src (17b) | dst-low-9 (bits 17..25). ONE round per block (per <= 2048).
__global__ void __launch_bounds__(256) k_binA(const int* __restrict__ src,
                                              const int* __restrict__ dst,
                                              int* __restrict__ gcur,
                                              uint* __restrict__ ebuf, int E) {
  __shared__ uint bins[NCB][BIN_D + 1];   // +1 pad
  __shared__ uint bcnt[NCB];
  int t = threadIdx.x;
  for (int j = t; j < NCB; j += 256) bcnt[j] = 0;
  const int per = (E + SC_BLOCKS - 1) / SC_BLOCKS;   // 2000
  int e0 = blockIdx.x * per, e1 = min(E, e0 + per);
  __syncthreads();
  #pragma unroll
  for (int r = 0; r < 8; ++r) {
    int i = e0 + r * 256 + t;
    if (i < e1) {
      uint s = (uint)src[i], d = (uint)dst[i];
      uint b = d >> CB_SH;
      uint rec = s | ((d & 511u) << 17);
      uint slot = atomicAdd(&bcnt[b], 1u);
      if (slot < BIN_D) bins[b][slot] = rec;
      else ebuf[(size_t)b * CAP + atomicAdd(&gcur[b], 1)] = rec;  // rare overflow
    }
  }
  __syncthreads();
  if (t < NCB) {                      // one thread per bucket: parallel flush
    uint c = bcnt[t]; if (c > BIN_D) c = BIN_D;
    if (c) {
      int base = atomicAdd(&gcur[t], (int)c);
      for (uint i = 0; i < c; ++i) ebuf[(size_t)t * CAP + base + i] = bins[t][i];
    }
  }
}

// ---------------- merged: degree count + scan -> row_ptr/dis + counting-sort scatter -> edges ----------------
__global__ void __launch_bounds__(512) k_csr(const uint* __restrict__ ebuf,
                                             const int* __restrict__ gcur,
                                             int* __restrict__ row_ptr,
                                             float* __restrict__ dis,
                                             uint* __restrict__ edges, int N, int E) {
  __shared__ uint sbuf[SORT_D];         // 35 KB
  __shared__ uint c[512];
  __shared__ uint wsum[8];
  int b = blockIdx.x, t = threadIdx.x, lane = t & 63, wv = t >> 6;
  c[t] = 0;

  // ebase = sum_{j<b} gcur[j]  (196 values, redundant per block)
  uint v = (t < b) ? (uint)gcur[t] : 0u;    // t<b<=195 implies t<NCB
  #pragma unroll
  for (int d = 32; d; d >>= 1) v += __shfl_xor(v, d, 64);
  if (lane == 0) wsum[wv] = v;
  __syncthreads();                      // covers c[] init + wsum
  uint ebase = 0;
  #pragma unroll
  for (int j = 0; j < 8; ++j) ebase += wsum[j];

  int cntb = gcur[b];
  const uint* __restrict__ eb = ebuf + (size_t)b * CAP;
  uint rec[RPT];                        // static indices only (no scratch)
  #pragma unroll
  for (int j = 0; j < RPT; ++j) {
    int i = t + j * 512;
    rec[j] = (i < cntb) ? eb[i] : 0xffffffffu;   // valid records < 2^26
  }
  #pragma unroll
  for (int j = 0; j < RPT; ++j)
    if (rec[j] != 0xffffffffu) atomicAdd(&c[rec[j] >> 17], 1u);
  __syncthreads();

  // block exclusive scan over 512 counters
  uint deg = c[t];
  uint x = deg;
  #pragma unroll
  for (int d = 1; d < 64; d <<= 1) {
    uint y = __shfl_up(x, (uint)d, 64);
    if (lane >= d) x += y;
  }
  if (lane == 63) wsum[wv] = x;
  __syncthreads();
  uint wexcl = 0;
  for (int j = 0; j < wv; ++j) wexcl += wsum[j];
  uint excl = wexcl + (x - deg);        // bucket-local exclusive prefix

  int g = (b << CB_SH) + t;
  if (g < N) {
    row_ptr[g] = (int)(ebase + excl);
    dis[g] = rsqrtf((float)deg + 1.0f);
  }
  if (b == 0 && t == 0) row_ptr[N] = E;

  c[t] = excl;                          // counter array becomes cursor array
  __syncthreads();
  #pragma unroll
  for (int j = 0; j < RPT; ++j)
    if (rec[j] != 0xffffffffu) {
      int pos = atomicAdd(&c[rec[j] >> 17], 1u);   // pos < cntb <= SORT_D always
      sbuf[pos] = rec[j] & 0x1ffffu;
    }
  __syncthreads();
  for (int i = t; i < cntb; i += 512)
    edges[ebase + i] = sbuf[i];
}

// ---------------- MFMA bf16 GEMM: Hb[M][FOUT](bf16) = dis[m] * (X[M][128] @ W[128][FOUT]) ----------------
// BM=128 rows/block, 512 threads (8 waves): wave wv -> row-block rb=wv&3, col-group cg=wv>>2.
// W pre-packed (k_setup) in LDS fragment layout -> staging is a straight uint4 copy.
template <int FOUT, bool BF16IN>
__global__ void __launch_bounds__(512) k_gemm(const void* __restrict__ Xv,
                                              const ushort* __restrict__ Wb,
                                              const float* __restrict__ dis,
                                              ushort* __restrict__ Hb, int M) {
  constexpr int NCT = FOUT / 32;        // column tiles (4 or 2)
  constexpr int TPW = NCT / 2;          // tiles per wave (2 or 1)
  __shared__ alignas(16) ushort Af[4 * 8 * 64 * 8];    // 32 KB, 128 rows
  __shared__ alignas(16) ushort Wf[NCT * 8 * 64 * 8];  // 32/16 KB
  __shared__ float diss[128];
  int t = threadIdx.x, lane = t & 63, wv = t >> 6;
  int m0 = blockIdx.x * 128;

  if (t < 128) {
    int gm = m0 + t;
    diss[t] = (gm < M) ? dis[gm] : 0.f;
  }
  {
    int m = t >> 2;                     // 0..127
    int gm = m0 + m;
    int rb = m >> 5, ml = m & 31;
    #pragma unroll
    for (int i = 0; i < 4; ++i) {
      int g = (t & 3) + i * 4;          // g = k>>3 in 0..15
      uint4 p = make_uint4(0u, 0u, 0u, 0u);
      if (gm < M) {
        if (BF16IN) {
          const ushort* X = (const ushort*)Xv;
          p = *reinterpret_cast<const uint4*>(X + (size_t)gm * 128 + g * 8);
        } else {
          const float* X = (const float*)Xv;
          float4 va = *reinterpret_cast<const float4*>(X + (size_t)gm * 128 + g * 8);
          float4 vb = *reinterpret_cast<const float4*>(X + (size_t)gm * 128 + g * 8 + 4);
          p.x = bf16_rne(va.x) | (bf16_rne(va.y) << 16);
          p.y = bf16_rne(va.z) | (bf16_rne(va.w) << 16);
          p.z = bf16_rne(vb.x) | (bf16_rne(vb.y) << 16);
          p.w = bf16_rne(vb.z) | (bf16_rne(vb.w) << 16);
        }
      }
      int kc = g >> 1, khi = g & 1;
      int ln = khi * 32 + ml;
      *reinterpret_cast<uint4*>(&Af[(((rb * 8 + kc) * 64) + ln) * 8]) = p;
    }
  }
  {
    constexpr int WU4 = 128 * FOUT * 2 / 16;   // uint4 count: 2048 (FOUT=128) / 1024 (FOUT=64)
    #pragma unroll
    for (int it = 0; it < WU4 / 512; ++it) {
      int idx = it * 512 + t;
      reinterpret_cast<uint4*>(Wf)[idx] = reinterpret_cast<const uint4*>(Wb)[idx];
    }
  }
  __syncthreads();

  f32x16 acc[TPW];
  #pragma unroll
  for (int tp = 0; tp < TPW; ++tp)
    #pragma unroll
    for (int r = 0; r < 16; ++r) acc[tp][r] = 0.f;

  int rb = wv & 3, cg = wv >> 2;
  #pragma unroll
  for (int kc = 0; kc < 8; ++kc) {
    bf16x8 a = *reinterpret_cast<bf16x8*>(&Af[((rb * 8 + kc) * 64 + lane) * 8]);
    #pragma unroll
    for (int tp = 0; tp < TPW; ++tp) {
      int c = cg * TPW + tp;
      bf16x8 bb = *reinterpret_cast<bf16x8*>(&Wf[((c * 8 + kc) * 64 + lane) * 8]);
      acc[tp] = __builtin_amdgcn_mfma_f32_32x32x16_bf16(a, bb, acc[tp], 0, 0, 0);
    }
  }

  // C/D layout: col=lane&31, row=(reg&3)+8*(reg>>2)+4*(lane>>5)
  #pragma unroll
  for (int tp = 0; tp < TPW; ++tp) {
    int col = (cg * TPW + tp) * 32 + (lane & 31);
    #pragma unroll
    for (int reg = 0; reg < 16; ++reg) {
      int lr = rb * 32 + 4 * (lane >> 5) + (reg & 3) + 8 * (reg >> 2);
      int row = m0 + lr;
      if (row < M) Hb[(size_t)row * FOUT + col] = (ushort)bf16_rne(acc[tp][reg] * diss[lr]);
    }
  }
}

// ---------------- aggregate F=128: one 16-lane group per node (4 nodes/wave), no reduction ----------------
__global__ void __launch_bounds__(256) k_agg128(const uint* __restrict__ hb,
                                                const int* __restrict__ row_ptr,
                                                const uint* __restrict__ edges,
                                                const float* __restrict__ dis,
                                                const float* __restrict__ bias,
                                                uint* __restrict__ outb, int N) {
  int t = threadIdx.x;
  int lane = t & 63, wv = t >> 6;
  int g16 = lane >> 4;                // node index within wave (0..3)
  int sl = lane & 15;                 // uint4 slot (8 features)
  int gbase = lane & 48;              // first lane of my 16-lane group
  int n = blockIdx.x * 16 + wv * 4 + g16;
  if (n >= N) return;
  const uint4* __restrict__ h4 = reinterpret_cast<const uint4*>(hb);  // 16 uint4/row
  int beg = row_ptr[n], end = row_ptr[n + 1];

  float acc[8];
  #pragma unroll
  for (int k = 0; k < 8; ++k) acc[k] = 0.f;

  int p = beg;
  for (; p + 8 <= end; p += 8) {        // 8 rows in flight per group (32/wave)
    uint r = edges[p + (lane & 7)];
    uint4 v[8];
    #pragma unroll
    for (int s = 0; s < 8; ++s) {
      uint rec = __shfl(r, gbase + s, 64);
      v[s] = h4[(size_t)rec * 16 + sl];
    }
    #pragma unroll
    for (int s = 0; s < 8; ++s) {
      acc[0] += blo(v[s].x);
      acc[1] += bhi(v[s].x);
      acc[2] += blo(v[s].y);
      acc[3] += bhi(v[s].y);
      acc[4] += blo(v[s].z);
      acc[5] += bhi(v[s].z);
      acc[6] += blo(v[s].w);
      acc[7] += bhi(v[s].w);
    }
  }
  if (p < end) {                        // remainder (<8), group-uniform guards
    int idx = p + (lane & 7);
    uint r = (idx < end) ? edges[idx] : 0u;
    #pragma unroll
    for (int s = 0; s < 8; ++s) {
      if (p + s < end) {
        uint rec = __shfl(r, gbase + s, 64);
        uint4 v = h4[(size_t)rec * 16 + sl];
        acc[0] += blo(v.x);
        acc[1] += bhi(v.x);
        acc[2] += blo(v.y);
        acc[3] += bhi(v.y);
        acc[4] += blo(v.z);
        acc[5] += bhi(v.z);
        acc[6] += blo(v.w);
        acc[7] += bhi(v.w);
      }
    }
  }

  float dn = dis[n];
  uint4 hv = h4[(size_t)n * 16 + sl];   // self row (already dis-scaled)
  const float4* b4 = reinterpret_cast<const float4*>(bias);
  float4 ba = b4[sl * 2], bb2 = b4[sl * 2 + 1];
  float o0 = fmaxf((acc[0] + blo(hv.x)) * dn + ba.x, 0.f);   // ReLU fused
  float o1 = fmaxf((acc[1] + bhi(hv.x)) * dn + ba.y, 0.f);
  float o2 = fmaxf((acc[2] + blo(hv.y)) * dn + ba.z, 0.f);
  float o3 = fmaxf((acc[3] + bhi(hv.y)) * dn + ba.w, 0.f);
  float o4 = fmaxf((acc[4] + blo(hv.z)) * dn + bb2.x, 0.f);
  float o5 = fmaxf((acc[5] + bhi(hv.z)) * dn + bb2.y, 0.f);
  float o6 = fmaxf((acc[6] + blo(hv.w)) * dn + bb2.z, 0.f);
  float o7 = fmaxf((acc[7] + bhi(hv.w)) * dn + bb2.w, 0.f);
  uint4 pb;
  pb.x = bf16_rne(o0) | (bf16_rne(o1) << 16);
  pb.y = bf16_rne(o2) | (bf16_rne(o3) << 16);
  pb.z = bf16_rne(o4) | (bf16_rne(o5) << 16);
  pb.w = bf16_rne(o6) | (bf16_rne(o7) << 16);
  reinterpret_cast<uint4*>(outb)[(size_t)n * 16 + sl] = pb;
}

// ---------------- aggregate F=64 + fused log_softmax: one 8-lane group per node (8 nodes/wave) ----------------
__global__ void __launch_bounds__(256) k_agg64(const uint* __restrict__ hb,
                                               const int* __restrict__ row_ptr,
                                               const uint* __restrict__ edges,
                                               const float* __restrict__ dis,
                                               const float* __restrict__ bias,
                                               float* __restrict__ out, int N) {
  int t = threadIdx.x;
  int lane = t & 63, wv = t >> 6;
  int g8 = lane >> 3;                 // node index within wave (0..7)
  int sl = lane & 7;                  // uint4 slot (8 features of 64)
  int gbase = lane & 56;              // first lane of my 8-lane group
  int n = blockIdx.x * 32 + wv * 8 + g8;
  if (n >= N) return;
  const uint4* __restrict__ h4 = reinterpret_cast<const uint4*>(hb);  // 8 uint4/row
  int beg = row_ptr[n], end = row_ptr[n + 1];

  float acc[8];
  #pragma unroll
  for (int k = 0; k < 8; ++k) acc[k] = 0.f;

  int p = beg;
  for (; p + 8 <= end; p += 8) {        // 8 rows in flight per group (64/wave)
    uint r = edges[p + sl];
    uint4 v[8];
    #pragma unroll
    for (int s = 0; s < 8; ++s) {
      uint rec = __shfl(r, gbase + s, 64);
      v[s] = h4[(size_t)rec * 8 + sl];
    }
    #pragma unroll
    for (int s = 0; s < 8; ++s) {
      acc[0] += blo(v[s].x);
      acc[1] += bhi(v[s].x);
      acc[2] += blo(v[s].y);
      acc[3] += bhi(v[s].y);
      acc[4] += blo(v[s].z);
      acc[5] += bhi(v[s].z);
      acc[6] += blo(v[s].w);
      acc[7] += bhi(v[s].w);
    }
  }
  if (p < end) {
    int idx = p + sl;
    uint r = (idx < end) ? edges[idx] : 0u;
    #pragma unroll
    for (int s = 0; s < 8; ++s) {
      if (p + s < end) {
        uint rec = __shfl(r, gbase + s, 64);
        uint4 v = h4[(size_t)rec * 8 + sl];
        acc[0] += blo(v.x);
        acc[1] += bhi(v.x);
        acc[2] += blo(v.y);
        acc[3] += bhi(v.y);
        acc[4] += blo(v.z);
        acc[5] += bhi(v.z);
        acc[6] += blo(v.w);
        acc[7] += bhi(v.w);
      }
    }
  }

  float dn = dis[n];
  uint4 hv = h4[(size_t)n * 8 + sl];    // self row (already dis-scaled)
  const float4* b4 = reinterpret_cast<const float4*>(bias);
  float4 ba = b4[sl * 2], bb2 = b4[sl * 2 + 1];
  float z[8];
  z[0] = (acc[0] + blo(hv.x)) * dn + ba.x;
  z[1] = (acc[1] + bhi(hv.x)) * dn + ba.y;
  z[2] = (acc[2] + blo(hv.y)) * dn + ba.z;
  z[3] = (acc[3] + bhi(hv.y)) * dn + ba.w;
  z[4] = (acc[4] + blo(hv.z)) * dn + bb2.x;
  z[5] = (acc[5] + bhi(hv.z)) * dn + bb2.y;
  z[6] = (acc[6] + blo(hv.w)) * dn + bb2.z;
  z[7] = (acc[7] + bhi(hv.w)) * dn + bb2.w;

  float m = z[0];
  #pragma unroll
  for (int k = 1; k < 8; ++k) m = fmaxf(m, z[k]);
  m = fmaxf(m, __shfl_xor(m, 1, 64));
  m = fmaxf(m, __shfl_xor(m, 2, 64));
  m = fmaxf(m, __shfl_xor(m, 4, 64));
  float e = 0.f;
  #pragma unroll
  for (int k = 0; k < 8; ++k) e += __expf(z[k] - m);
  e += __shfl_xor(e, 1, 64);
  e += __shfl_xor(e, 2, 64);
  e += __shfl_xor(e, 4, 64);
  float lse = m + __logf(e);

  float4* orow = reinterpret_cast<float4*>(out + (size_t)n * 64);
  orow[sl * 2]     = make_float4(z[0] - lse, z[1] - lse, z[2] - lse, z[3] - lse);
  orow[sl * 2 + 1] = make_float4(z[4] - lse, z[5] - lse, z[6] - lse, z[7] - lse);
}

extern "C" void kernel_launch(void* const* d_in, const int* in_sizes, int n_in,
                              void* d_out, int out_size, void* d_ws, size_t ws_size,
                              hipStream_t stream) {
  const float* x  = (const float*)d_in[0];
  const int*   ei = (const int*)d_in[1];
  const float* W0 = (const float*)d_in[2];
  const float* b0 = (const float*)d_in[3];
  const float* W1 = (const float*)d_in[4];
  const float* b1 = (const float*)d_in[5];
  const float* W2 = (const float*)d_in[6];
  const float* b2 = (const float*)d_in[7];
  float* out = (float*)d_out;

  const int N = NN, E = NE;
  const int* src = ei;
  const int* dst = ei + E;

  char* ws = (char*)d_ws;
  size_t off = 0;
  auto alloc = [&](size_t bytes) -> void* {
    off = (off + 255) & ~(size_t)255;
    void* p = ws + off;
    off += bytes;
    return p;
  };
  float*  dis     = (float*)alloc((size_t)N * 4);
  int*    row_ptr = (int*)alloc((size_t)(N + 1) * 4);
  int*    gcur    = (int*)alloc((size_t)NCB * 4);
  uint*   ebuf    = (uint*)alloc((size_t)NCB * CAP * 4);
  uint*   edges   = (uint*)alloc((size_t)E * 4);
  ushort* bufAb   = (ushort*)alloc((size_t)N * 128 * 2);  // gemm bf16 out
  ushort* bufBb   = (ushort*)alloc((size_t)N * 128 * 2);  // agg bf16 out / gemm in
  ushort* W0b     = (ushort*)alloc(128 * 128 * 2);
  ushort* W1b     = (ushort*)alloc(128 * 128 * 2);
  ushort* W2b     = (ushort*)alloc(128 * 64 * 2);

  // ---- CSR build + weight pre-pack (9 launches total) ----
  k_setup<<<4, 256, 0, stream>>>(W0, W1, W2, W0b, W1b, W2b, gcur);
  k_binA<<<SC_BLOCKS, 256, 0, stream>>>(src, dst, gcur, ebuf, E);
  k_csr<<<NCB, 512, 0, stream>>>(ebuf, gcur, row_ptr, dis, edges, N, E);

  const int gemm_grid = (N + 127) / 128;  // 782 (128 rows/block, 8 waves)
  const int agg128_grid = (N + 15) / 16;  // 6250 (16 nodes/block, 4 per wave)
  const int agg64_grid = (N + 31) / 32;   // 3125 (32 nodes/block, 8 per wave)

  // ---- layer 0 ----
  k_gemm<128, false><<<gemm_grid, 512, 0, stream>>>(x, W0b, dis, bufAb, N);
  k_agg128<<<agg128_grid, 256, 0, stream>>>((const uint*)bufAb, row_ptr, edges, dis, b0, (uint*)bufBb, N);
  // ---- layer 1 ----
  k_gemm<128, true><<<gemm_grid, 512, 0, stream>>>(bufBb, W1b, dis, bufAb, N);
  k_agg128<<<agg128_grid, 256, 0, stream>>>((const uint*)bufAb, row_ptr, edges, dis, b1, (uint*)bufBb, N);
  // ---- layer 2 (fused log_softmax epilogue) ----
  k_gemm<64, true><<<gemm_grid, 512, 0, stream>>>(bufBb, W2b, dis, bufAb, N);
  k_agg64<<<agg64_grid, 256, 0, stream>>>((const uint*)bufAb, row_ptr, edges, dis, b2, out, N);
}